// Round 8
// baseline (138.454 us; speedup 1.0000x reference)
//
#include <hip/hip_runtime.h>
#include <hip/hip_bf16.h>

using bf16 = __hip_bfloat16;
typedef __attribute__((ext_vector_type(8))) short short8;
typedef __attribute__((ext_vector_type(4))) float f32x4;
typedef __attribute__((ext_vector_type(16))) float f32x16;

__device__ __constant__ int c_dil[8] = {1, 2, 4, 8, 1, 2, 4, 8};

__device__ inline void store1(float* p, float v) { *p = v; }
__device__ inline void store1(bf16* p, float v) { *p = __float2bfloat16(v); }

// async global->LDS, 16 B per lane; LDS dest wave-uniform base (+ lane*16 by HW)
__device__ inline void gload_lds16(const void* g, void* l) {
    __builtin_amdgcn_global_load_lds(
        (const __attribute__((address_space(1))) unsigned int*)g,
        (__attribute__((address_space(3))) unsigned int*)l, 16, 0, 0);
}

template <int N> __device__ inline void vwait() {
    asm volatile("s_waitcnt vmcnt(%0)" :: "n"(N) : "memory");
}

// manual RNE f32->bf16
__device__ inline unsigned short f2bf(float f) {
    const unsigned u = __float_as_uint(f);
    return (unsigned short)((u + 0x7fffu + ((u >> 16) & 1u)) >> 16);
}
__device__ inline float bf2f(unsigned short h) { return __uint_as_float(((unsigned)h) << 16); }

// ---------------- fused convert: f32 -> bf16 ----------------
// mode 0: row = ld, plain;  mode 1: row = 1024, [hi|lo] (x);  mode 2: row = 1024, [hi|hi] (QK w)
__device__ inline void conv_block(const float* __restrict__ src, bf16* __restrict__ dst,
                                  int ld, int mode, int idx) {
    const float4 v = *reinterpret_cast<const float4*>(src + idx);
    const int r = idx >> 9, c = idx & 511;
    bf16* d = dst + (size_t)r * ld + c;
    const float vv[4] = {v.x, v.y, v.z, v.w};
    ushort4 hi, lo;
    unsigned short* hp = &hi.x; unsigned short* lp = &lo.x;
#pragma unroll
    for (int j = 0; j < 4; ++j) {
        hp[j] = f2bf(vv[j]);
        lp[j] = f2bf(vv[j] - bf2f(hp[j]));
    }
    *reinterpret_cast<ushort4*>(d) = hi;
    if (mode == 1) *reinterpret_cast<ushort4*>(d + 512) = lo;
    else if (mode == 2) *reinterpret_cast<ushort4*>(d + 512) = hi;
}

__global__ __launch_bounds__(256) void conv_all(
    const float* __restrict__ x,  const float* __restrict__ qw, const float* __restrict__ kw,
    const float* __restrict__ vw, const float* __restrict__ ow,
    const float* __restrict__ qb, const float* __restrict__ kb,
    bf16* A2, bf16* Wqk, bf16* Wv, bf16* Wo, float* bqk)
{
    const int b = blockIdx.x, t = threadIdx.x;
    if (b < 2048)       conv_block(x,  A2,                       1024, 1, (b * 256 + t) * 4);
    else if (b < 2304)  conv_block(qw, Wqk,                      1024, 2, ((b - 2048) * 256 + t) * 4);
    else if (b < 3584)  conv_block(kw, Wqk + (size_t)512 * 1024, 1024, 2, ((b - 2304) * 256 + t) * 4);
    else if (b < 4864)  conv_block(vw, Wv,                        512, 0, ((b - 3584) * 256 + t) * 4);
    else if (b < 5120)  conv_block(ow, Wo,                        512, 0, ((b - 4864) * 256 + t) * 4);
    else { const int i = (b - 5120) * 256 + t; bqk[i] = (i < 512) ? qb[i] : kb[i - 512]; }
}

// ---------------- QKV GEMM: 256x128 tile, mfma 32x32x16, BK=32, 4 waves (2x2) ----------
// Wave-tile 128x64 = 4m x 2n fragments of 32x32; per K-step 16 MFMA + 12 ds_read_b128.
// 3-buffer LDS (72 KB -> 2 blocks/CU), prefetch depth 2, counted vmcnt, raw barriers.
// No LDS swizzle: 32-row fragment reads at 64 B row stride are naturally <=2-way (free).
// Dual-target: col-tile bx < nx0 -> target 0 (K=1024 exact-x), else target 1 (K=512).
__global__ __launch_bounds__(256) void gemm_qkv(
    const bf16* __restrict__ A, int lda,
    const bf16* __restrict__ W0, int ldw0, const float* __restrict__ b0,
    bf16* __restrict__ C0, int ldc0, int nt0, int nx0,
    const bf16* __restrict__ W1, int ldw1, const float* __restrict__ b1,
    bf16* __restrict__ C1, int ldc1, int nt1)
{
    __shared__ short As[3][256 * 32];   // 3 x 16 KB
    __shared__ short Bs[3][128 * 32];   // 3 x 8 KB

    const int tid = threadIdx.x, wid = tid >> 6, lane = tid & 63;

    // XCD mapping: 8 XCDs x 88 blocks; per XCD 2 M-rows x 44 cols
    const int xcd = (int)blockIdx.x & 7;
    const int i   = (int)blockIdx.x >> 3;      // 0..87
    const int by  = xcd * 2 + (i & 1);         // 0..15
    const int bx  = i >> 1;                    // 0..43

    const int bm = by * 256;
    const bool t0 = bx < nx0;
    const int bn = (t0 ? bx : bx - nx0) * 128;
    const bf16* W      = t0 ? W0 : W1;
    const int   ldw    = t0 ? ldw0 : ldw1;
    const float* bias  = t0 ? b0 : b1;
    const int   nsteps = t0 ? nt0 : nt1;

    // ---- staging: A 16 KB (4 loads/thread) + B 8 KB (2 loads/thread), linear LDS ----
    const int srow = lane >> 2;               // 0..15
    const int scol = (lane & 3) << 4;         // 0,16,32,48 bytes within 64 B k-row
    const char* pA0 = (const char*)A + (size_t)(bm + (wid * 4 + 0) * 16 + srow) * lda * 2 + scol;
    const char* pA1 = (const char*)A + (size_t)(bm + (wid * 4 + 1) * 16 + srow) * lda * 2 + scol;
    const char* pA2 = (const char*)A + (size_t)(bm + (wid * 4 + 2) * 16 + srow) * lda * 2 + scol;
    const char* pA3 = (const char*)A + (size_t)(bm + (wid * 4 + 3) * 16 + srow) * lda * 2 + scol;
    const char* pB0 = (const char*)W + (size_t)(bn + (wid * 2 + 0) * 16 + srow) * ldw * 2 + scol;
    const char* pB1 = (const char*)W + (size_t)(bn + (wid * 2 + 1) * 16 + srow) * ldw * 2 + scol;

    f32x16 acc[4][2];
#pragma unroll
    for (int m = 0; m < 4; ++m)
#pragma unroll
        for (int n = 0; n < 2; ++n)
#pragma unroll
            for (int j = 0; j < 16; ++j) acc[m][n][j] = 0.f;

    // ---- read offsets (shorts): frag row/col = lane&31, k-block = (lane>>5)*8 ----
    const int l31 = lane & 31;
    const int kblk = (lane >> 5) * 8;
    const int wrM = wid >> 1, wcN = wid & 1;
    int offA[2][4], offB[2][2];
#pragma unroll
    for (int ks = 0; ks < 2; ++ks) {
#pragma unroll
        for (int m = 0; m < 4; ++m)
            offA[ks][m] = (wrM * 128 + m * 32 + l31) * 32 + ks * 16 + kblk;
#pragma unroll
        for (int n = 0; n < 2; ++n)
            offB[ks][n] = (wcN * 64 + n * 32 + l31) * 32 + ks * 16 + kblk;
    }

    auto stage = [&](int buf) {
        char* a = (char*)As[buf];
        char* b = (char*)Bs[buf];
        gload_lds16(pA0, a + (wid * 4 + 0) * 1024);
        gload_lds16(pA1, a + (wid * 4 + 1) * 1024);
        gload_lds16(pA2, a + (wid * 4 + 2) * 1024);
        gload_lds16(pA3, a + (wid * 4 + 3) * 1024);
        gload_lds16(pB0, b + (wid * 2 + 0) * 1024);
        gload_lds16(pB1, b + (wid * 2 + 1) * 1024);
        pA0 += 64; pA1 += 64; pA2 += 64; pA3 += 64; pB0 += 64; pB1 += 64;
    };

    stage(0);
    stage(1);

    int cur = 0;
    for (int s = 0; s < nsteps; ++s) {
        // issue tile s+2 into slot of tile s-1 (fully consumed last step); counted
        // waits keep tiles s+1, s+2 in flight across the raw barriers (T3/T4).
        if (s + 2 < nsteps) {
            stage(cur == 0 ? 2 : cur - 1);
            vwait<12>();
        } else if (s + 1 < nsteps) {
            vwait<6>();
        } else {
            vwait<0>();
        }
        __builtin_amdgcn_s_barrier();          // all waves' tile-s loads landed
        __builtin_amdgcn_sched_barrier(0);

        short8 a0[4], a1[4], bb0[2], bb1[2];
#pragma unroll
        for (int m = 0; m < 4; ++m) {
            a0[m] = *(const short8*)&As[cur][offA[0][m]];
            a1[m] = *(const short8*)&As[cur][offA[1][m]];
        }
#pragma unroll
        for (int n = 0; n < 2; ++n) {
            bb0[n] = *(const short8*)&Bs[cur][offB[0][n]];
            bb1[n] = *(const short8*)&Bs[cur][offB[1][n]];
        }

        __builtin_amdgcn_s_setprio(1);
#pragma unroll
        for (int m = 0; m < 4; ++m)
#pragma unroll
            for (int n = 0; n < 2; ++n)
                acc[m][n] = __builtin_amdgcn_mfma_f32_32x32x16_bf16(a0[m], bb0[n], acc[m][n], 0, 0, 0);
#pragma unroll
        for (int m = 0; m < 4; ++m)
#pragma unroll
            for (int n = 0; n < 2; ++n)
                acc[m][n] = __builtin_amdgcn_mfma_f32_32x32x16_bf16(a1[m], bb1[n], acc[m][n], 0, 0, 0);
        __builtin_amdgcn_s_setprio(0);

        __builtin_amdgcn_s_barrier();          // reads of buf cur done -> safe to restage
        __builtin_amdgcn_sched_barrier(0);
        cur = (cur == 2) ? 0 : cur + 1;
    }

    // epilogue: 32x32 C/D layout col=lane&31, row=(reg&3)+8*(reg>>2)+4*(lane>>5)
    const int rbase = 4 * (lane >> 5);
#pragma unroll
    for (int m = 0; m < 4; ++m) {
#pragma unroll
        for (int n = 0; n < 2; ++n) {
            const int col = bn + wcN * 64 + n * 32 + l31;
            const float bv = bias[col];
#pragma unroll
            for (int j = 0; j < 16; ++j) {
                const int row = bm + wrM * 128 + m * 32 + (j & 3) + 8 * (j >> 2) + rbase;
                const float v = acc[m][n][j] + bv;
                if (t0) store1(C0 + (size_t)row * ldc0 + col, v);
                else    store1(C1 + (size_t)row * ldc1 + col, v);
            }
        }
    }
}

// ---------------- O-projection GEMM, 128 x 64 tile, 16x16x32 (proven) ----------------
template <int BN, typename TC>
__global__ __launch_bounds__(256) void gemm128(
    const bf16* __restrict__ A, int lda, int cw, int rpx,
    const bf16* __restrict__ W0, int ldw0, const float* __restrict__ b0,
    TC* __restrict__ C0, int ldc0, int nt0, int nx0)
{
    constexpr int NF = BN / 32;
    constexpr int NLOAD = (BN == 128) ? 4 : 3;
    __shared__ short As[4][128 * 32];
    __shared__ short Bs[4][BN * 32];

    const int tid = threadIdx.x, wid = tid >> 6, lane = tid & 63;

    const int xcd = (int)blockIdx.x & 7;
    const int i   = (int)blockIdx.x >> 3;
    const int grp = rpx * cw;
    const int cc = i / grp, w2 = i % grp;
    const int rr = w2 / cw, c = w2 % cw;
    const int bx = cc * cw + c;
    const int by = xcd * rpx + rr;

    const int bm = by * 128;
    const int bn = bx * BN;
    const int nsteps = nt0;

    const int srow = lane >> 2;
    const int ssw  = (((lane & 3) ^ ((lane >> 3) & 3)) << 4);
    const char* pA0 = (const char*)A + (size_t)(bm + wid * 16 + srow) * lda * 2 + ssw;
    const char* pA1 = pA0 + (size_t)64 * lda * 2;
    const char* pB0 = (const char*)W0 + (size_t)(bn + wid * 16 + srow) * ldw0 * 2 + ssw;

    f32x4 acc[4][NF];
#pragma unroll
    for (int m = 0; m < 4; ++m)
#pragma unroll
        for (int n = 0; n < NF; ++n) acc[m][n] = f32x4{0.f, 0.f, 0.f, 0.f};

    const int lr16 = lane & 15;
    const int wsw8 = (((lane >> 4) ^ ((lr16 >> 1) & 3)) << 3);
    const int wr = wid >> 1, wc = wid & 1;
    int offA[4], offB[NF];
#pragma unroll
    for (int m = 0; m < 4; ++m) offA[m] = (wr * 4 + m) * 512 + lr16 * 32 + wsw8;
#pragma unroll
    for (int n = 0; n < NF; ++n) offB[n] = (wc * NF + n) * 512 + lr16 * 32 + wsw8;

    auto stage = [&](int buf) {
        gload_lds16(pA0, (char*)As[buf] + wid * 1024);
        gload_lds16(pA1, (char*)As[buf] + (wid + 4) * 1024);
        gload_lds16(pB0, (char*)Bs[buf] + wid * 1024);
        pA0 += 64; pA1 += 64; pB0 += 64;
    };

    stage(0);
    stage(1);
    stage(2);

    for (int s = 0; s < nsteps; ++s) {
        const int cur = s & 3;
        if (s + 3 < nsteps) {
            stage((s + 3) & 3);
            vwait<3 * NLOAD>();
        } else if (s + 2 < nsteps) {
            vwait<2 * NLOAD>();
        } else if (s + 1 < nsteps) {
            vwait<NLOAD>();
        } else {
            vwait<0>();
        }
        __builtin_amdgcn_s_barrier();
        __builtin_amdgcn_sched_barrier(0);

        short8 af[4], bw[NF];
#pragma unroll
        for (int m = 0; m < 4; ++m)
            af[m] = *(const short8*)&As[cur][offA[m]];
#pragma unroll
        for (int n = 0; n < NF; ++n)
            bw[n] = *(const short8*)&Bs[cur][offB[n]];

        __builtin_amdgcn_s_setprio(1);
#pragma unroll
        for (int m = 0; m < 4; ++m)
#pragma unroll
            for (int n = 0; n < NF; ++n)
                acc[m][n] = __builtin_amdgcn_mfma_f32_16x16x32_bf16(af[m], bw[n], acc[m][n], 0, 0, 0);
        __builtin_amdgcn_s_setprio(0);

        __builtin_amdgcn_s_barrier();
        __builtin_amdgcn_sched_barrier(0);
    }

    const int r4 = (lane >> 4) * 4;
#pragma unroll
    for (int m = 0; m < 4; ++m) {
#pragma unroll
        for (int n = 0; n < NF; ++n) {
            const int col = bn + wc * (NF * 16) + n * 16 + lr16;
            const float bv = b0[col];
#pragma unroll
            for (int jj = 0; jj < 4; ++jj) {
                const int row = bm + wr * 64 + m * 16 + r4 + jj;
                store1(C0 + (size_t)row * ldc0 + col, acc[m][n][jj] + bv);
            }
        }
    }
}

// ---------------- local attention stitch ----------------
__global__ __launch_bounds__(256) void attn_k(
    const bf16* __restrict__ PQK, const bf16* __restrict__ PV, bf16* __restrict__ Aout)
{
    const int lane = threadIdx.x & 63;
    const int wave = threadIdx.x >> 6;
    const int task = blockIdx.x * 4 + wave;  // 0..32767
    const int h  = task & 7;
    const int bl = task >> 3;
    const int l  = bl & 2047;
    const int d  = c_dil[h];

    const float q = __bfloat162float(PQK[(size_t)bl * 3072 + h * 64 + lane]);

    float logits[5], vvals[5];
#pragma unroll
    for (int kk = 0; kk < 5; ++kk) {
        const int pos = l + (kk - 2) * d;
        const bool ok = (pos >= 0) && (pos < 2048);
        float kv = 0.f, vv = 0.f;
        if (ok) {
            const size_t rb = (size_t)(bl - l + pos);
            kv = __bfloat162float(PQK[rb * 3072 + 512 + (h * 5 + kk) * 64 + lane]);
            vv = __bfloat162float(PV[rb * 2560 + (h * 5 + kk) * 64 + lane]);
        }
        vvals[kk] = vv;
        float lg = q * kv;
#pragma unroll
        for (int s = 32; s; s >>= 1) lg += __shfl_xor(lg, s);
        logits[kk] = lg;  // OOB -> 0, matches reference (zero-padded content, zero bias)
    }

    float mx = logits[0];
#pragma unroll
    for (int kk = 1; kk < 5; ++kk) mx = fmaxf(mx, logits[kk]);
    float e[5], ssum = 0.f;
#pragma unroll
    for (int kk = 0; kk < 5; ++kk) { e[kk] = __expf(logits[kk] - mx); ssum += e[kk]; }
    float acc = 0.f;
#pragma unroll
    for (int kk = 0; kk < 5; ++kk) acc += e[kk] * vvals[kk];
    acc *= 0.125f / ssum;

    Aout[(size_t)bl * 512 + h * 64 + lane] = __float2bfloat16(acc);
}

// ---------------- launch ----------------
extern "C" void kernel_launch(void* const* d_in, const int* in_sizes, int n_in,
                              void* d_out, int out_size, void* d_ws, size_t ws_size,
                              hipStream_t stream)
{
    const float* x   = (const float*)d_in[0];
    const float* q_w = (const float*)d_in[1];
    const float* q_b = (const float*)d_in[2];
    const float* k_w = (const float*)d_in[3];
    const float* k_b = (const float*)d_in[4];
    const float* v_w = (const float*)d_in[5];
    const float* v_b = (const float*)d_in[6];
    const float* o_w = (const float*)d_in[7];
    const float* o_b = (const float*)d_in[8];
    float* out = (float*)d_out;

    const int M = 4096;

    // workspace: 8 + 6 + 2.5 + 0.5 + 0.012 + 24 + 20 = 61.0 MB
    char* p = (char*)d_ws;
    bf16* A2  = (bf16*)p;  p += (size_t)M * 1024 * 2;       // [x_hi | x_lo]
    bf16* Wqk = (bf16*)p;  p += (size_t)3072 * 1024 * 2;    // [w_hi | w_hi]
    bf16* Wv  = (bf16*)p;  p += (size_t)2560 * 512 * 2;
    bf16* Wo  = (bf16*)p;  p += (size_t)512 * 512 * 2;
    float* bqk = (float*)p; p += 3072 * 4;
    bf16* PQK = (bf16*)p;  p += (size_t)M * 3072 * 2;
    bf16* PV  = (bf16*)p;
    bf16* Aout = A2;  // A2 dead after the QKV GEMM; reuse for attention output

    conv_all<<<dim3(5132), dim3(256), 0, stream>>>(x, q_w, k_w, v_w, o_w, q_b, k_b,
                                                   A2, Wqk, Wv, Wo, bqk);
    // fused QKV: col-tiles 0-23 -> PQK (K=1024 exact-x), 24-43 -> PV (K=512, hi half of A)
    // grid 704 = 8 XCD x (2 M-rows x 44 cols)
    gemm_qkv<<<dim3(704), dim3(256), 0, stream>>>(
        A2, 1024,
        Wqk, 1024, bqk, PQK, 3072, 32, 24,
        Wv,  512,  v_b, PV,  2560, 16);
    attn_k<<<dim3(8192), dim3(256), 0, stream>>>(PQK, PV, Aout);
    // grid 256 = 8 XCD x (4 rows x 8 cols)
    gemm128<64, float><<<dim3(256), dim3(256), 0, stream>>>(
        Aout, 512, /*cw*/8, /*rpx*/4,
        Wo, 512, o_b, out, 512, 16, 8);
}

// Round 9
// 90.748 us; speedup vs baseline: 1.5257x; 1.5257x over previous
//
#include <hip/hip_runtime.h>
#include <hip/hip_bf16.h>

using bf16 = __hip_bfloat16;
typedef __attribute__((ext_vector_type(8))) short short8;
typedef __attribute__((ext_vector_type(4))) float f32x4;

__device__ __constant__ int c_dil[8] = {1, 2, 4, 8, 1, 2, 4, 8};

__device__ inline void store1(float* p, float v) { *p = v; }
__device__ inline void store1(bf16* p, float v) { *p = __float2bfloat16(v); }

// async global->LDS, 16 B per lane; LDS dest wave-uniform base (+ lane*16 by HW)
__device__ inline void gload_lds16(const void* g, void* l) {
    __builtin_amdgcn_global_load_lds(
        (const __attribute__((address_space(1))) unsigned int*)g,
        (__attribute__((address_space(3))) unsigned int*)l, 16, 0, 0);
}

template <int N> __device__ inline void vwait() {
    asm volatile("s_waitcnt vmcnt(%0)" :: "n"(N) : "memory");
}
__device__ inline void lgkm0_fence() {
    asm volatile("s_waitcnt lgkmcnt(0)" ::: "memory");
    __builtin_amdgcn_sched_barrier(0);
}
__device__ inline void barrier_pin() {
    __builtin_amdgcn_s_barrier();
    __builtin_amdgcn_sched_barrier(0);
}

// manual RNE f32->bf16
__device__ inline unsigned short f2bf(float f) {
    const unsigned u = __float_as_uint(f);
    return (unsigned short)((u + 0x7fffu + ((u >> 16) & 1u)) >> 16);
}
__device__ inline float bf2f(unsigned short h) { return __uint_as_float(((unsigned)h) << 16); }

// ---------------- fused convert: f32 -> bf16 ----------------
// mode 0: row = ld, plain;  mode 1: row = 1024, [hi|lo] (x);  mode 2: row = 1024, [hi|hi] (QK w)
__device__ inline void conv_block(const float* __restrict__ src, bf16* __restrict__ dst,
                                  int ld, int mode, int idx) {
    const float4 v = *reinterpret_cast<const float4*>(src + idx);
    const int r = idx >> 9, c = idx & 511;
    bf16* d = dst + (size_t)r * ld + c;
    const float vv[4] = {v.x, v.y, v.z, v.w};
    ushort4 hi, lo;
    unsigned short* hp = &hi.x; unsigned short* lp = &lo.x;
#pragma unroll
    for (int j = 0; j < 4; ++j) {
        hp[j] = f2bf(vv[j]);
        lp[j] = f2bf(vv[j] - bf2f(hp[j]));
    }
    *reinterpret_cast<ushort4*>(d) = hi;
    if (mode == 1) *reinterpret_cast<ushort4*>(d + 512) = lo;
    else if (mode == 2) *reinterpret_cast<ushort4*>(d + 512) = hi;
}

__global__ __launch_bounds__(256) void conv_all(
    const float* __restrict__ x,  const float* __restrict__ qw, const float* __restrict__ kw,
    const float* __restrict__ vw, const float* __restrict__ ow,
    const float* __restrict__ qb, const float* __restrict__ kb,
    bf16* A2, bf16* Wqk, bf16* Wv, bf16* Wo, float* bqk)
{
    const int b = blockIdx.x, t = threadIdx.x;
    if (b < 2048)       conv_block(x,  A2,                       1024, 1, (b * 256 + t) * 4);
    else if (b < 2304)  conv_block(qw, Wqk,                      1024, 2, ((b - 2048) * 256 + t) * 4);
    else if (b < 3584)  conv_block(kw, Wqk + (size_t)512 * 1024, 1024, 2, ((b - 2304) * 256 + t) * 4);
    else if (b < 4864)  conv_block(vw, Wv,                        512, 0, ((b - 3584) * 256 + t) * 4);
    else if (b < 5120)  conv_block(ow, Wo,                        512, 0, ((b - 4864) * 256 + t) * 4);
    else { const int i = (b - 5120) * 256 + t; bqk[i] = (i < 512) ? qb[i] : kb[i - 512]; }
}

// ---------------- QKV GEMM: 256x256 tile, BK=64, 8 waves (2x4), 8-phase schedule -------
// Per K-tile: 4 phases of {ds_read subtile || prefetch -> barrier -> lgkmcnt(0) ->
// setprio(1) 16 MFMA setprio(0) -> barrier}; vmcnt(0) only at the tile boundary.
// LDS [256][64] shorts/operand/buffer (2 buffers, 128 KB). Swizzle: 16B slot within each
// 128 B row: phys_slot = logical_slot ^ (row&7); applied inverse on the staging SOURCE
// (linear gload_lds dest) and forward on the ds_read offset (rule 21). 2-way max = free.
// Dual-target: col-tile bx < nx0 -> PQK (K=1024 exact-x), else -> PV (K=512, hi half of A).
__global__ __launch_bounds__(512, 2) void gemm8p(
    const bf16* __restrict__ A, int lda,
    const bf16* __restrict__ W0, int ldw0, const float* __restrict__ b0,
    bf16* __restrict__ C0, int ldc0, int nt0, int nx0,
    const bf16* __restrict__ W1, int ldw1, const float* __restrict__ b1,
    bf16* __restrict__ C1, int ldc1, int nt1)
{
    __shared__ short As[2][256 * 64];   // 2 x 32 KB
    __shared__ short Bs[2][256 * 64];   // 2 x 32 KB

    const int tid = threadIdx.x, wid = tid >> 6, lane = tid & 63;

    // XCD mapping: per XCD 2 row-panels x 22 cols (QK cols first for load balance)
    const int xcd = (int)blockIdx.x & 7;
    const int j   = (int)blockIdx.x >> 3;     // 0..43
    const int by  = xcd * 2 + (j & 1);        // 0..15
    const int bx  = j >> 1;                   // 0..21

    const int bm = by * 256;
    const bool t0 = bx < nx0;
    const int bn = (t0 ? bx : bx - nx0) * 256;
    const bf16* W      = t0 ? W0 : W1;
    const int   ldw    = t0 ? ldw0 : ldw1;
    const float* bias  = t0 ? b0 : b1;
    const int   nsteps = t0 ? nt0 : nt1;

    // ---- staging: per thread 4 A-chunks + 4 B-chunks per K-tile (16 B each) ----
    // chunk c = i*512 + tid; row = i*64 + (tid>>3); logical slot = (tid&7) ^ ((tid>>3)&7)
    const int sslot = ((tid & 7) ^ ((tid >> 3) & 7)) << 4;   // bytes
    const char* pA[4];
    const char* pB[4];
#pragma unroll
    for (int i = 0; i < 4; ++i) {
        const int row = i * 64 + (tid >> 3);
        pA[i] = (const char*)A + (size_t)(bm + row) * lda * 2 + sslot;
        pB[i] = (const char*)W + (size_t)(bn + row) * ldw * 2 + sslot;
    }

    auto stageA = [&](int kt1) {
        char* d = (char*)As[kt1 & 1];
#pragma unroll
        for (int i = 0; i < 4; ++i) { gload_lds16(pA[i], d + i * 8192 + wid * 1024); pA[i] += 128; }
    };
    auto stageB = [&](int kt1) {
        char* d = (char*)Bs[kt1 & 1];
#pragma unroll
        for (int i = 0; i < 4; ++i) { gload_lds16(pB[i], d + i * 8192 + wid * 1024); pB[i] += 128; }
    };

    f32x4 acc[8][4];
#pragma unroll
    for (int m = 0; m < 8; ++m)
#pragma unroll
        for (int n = 0; n < 4; ++n) acc[m][n] = f32x4{0.f, 0.f, 0.f, 0.f};

    // ---- read offsets (short units): off = row*64 + ((ks*32 + hi8) ^ swz) ----
    const int lr16 = lane & 15;
    const int hi8  = (lane >> 4) * 8;
    const int swz  = (lr16 & 7) << 3;
    const int k0   = hi8 ^ swz;          // ks = 0
    const int k1   = (32 + hi8) ^ swz;   // ks = 1
    const int wrM = wid >> 2, wcN = wid & 3;
    const int arow0 = wrM * 128 + lr16;        // + m*16
    const int brow0 = wcN * 64 + lr16;         // + n*16

    // prologue: stage tile 0, drain, fence
    stageA(0); stageB(0);
    vwait<0>();
    barrier_pin();

    for (int kt = 0; kt < nsteps; ++kt) {
        const short* a  = As[kt & 1];
        const short* bb = Bs[kt & 1];
        const bool pf = (kt + 1 < nsteps);
        short8 af[4], bw0[4], bw1[4];

        // ---- phase 0: A half0 ks0 + B ks0 ; prefetch A(kt+1) ----
#pragma unroll
        for (int m = 0; m < 4; ++m) af[m] = *(const short8*)&a[(arow0 + m * 16) * 64 + k0];
#pragma unroll
        for (int n = 0; n < 4; ++n) bw0[n] = *(const short8*)&bb[(brow0 + n * 16) * 64 + k0];
        if (pf) stageA(kt + 1);
        barrier_pin();
        lgkm0_fence();
        __builtin_amdgcn_s_setprio(1);
#pragma unroll
        for (int m = 0; m < 4; ++m)
#pragma unroll
            for (int n = 0; n < 4; ++n)
                acc[m][n] = __builtin_amdgcn_mfma_f32_16x16x32_bf16(af[m], bw0[n], acc[m][n], 0, 0, 0);
        __builtin_amdgcn_s_setprio(0);
        barrier_pin();

        // ---- phase 1: A half1 ks0 ; prefetch B(kt+1) ----
#pragma unroll
        for (int m = 0; m < 4; ++m) af[m] = *(const short8*)&a[(arow0 + 64 + m * 16) * 64 + k0];
        if (pf) stageB(kt + 1);
        barrier_pin();
        lgkm0_fence();
        __builtin_amdgcn_s_setprio(1);
#pragma unroll
        for (int m = 0; m < 4; ++m)
#pragma unroll
            for (int n = 0; n < 4; ++n)
                acc[4 + m][n] = __builtin_amdgcn_mfma_f32_16x16x32_bf16(af[m], bw0[n], acc[4 + m][n], 0, 0, 0);
        __builtin_amdgcn_s_setprio(0);
        barrier_pin();

        // ---- phase 2: A half0 ks1 + B ks1 ----
#pragma unroll
        for (int m = 0; m < 4; ++m) af[m] = *(const short8*)&a[(arow0 + m * 16) * 64 + k1];
#pragma unroll
        for (int n = 0; n < 4; ++n) bw1[n] = *(const short8*)&bb[(brow0 + n * 16) * 64 + k1];
        barrier_pin();
        lgkm0_fence();
        __builtin_amdgcn_s_setprio(1);
#pragma unroll
        for (int m = 0; m < 4; ++m)
#pragma unroll
            for (int n = 0; n < 4; ++n)
                acc[m][n] = __builtin_amdgcn_mfma_f32_16x16x32_bf16(af[m], bw1[n], acc[m][n], 0, 0, 0);
        __builtin_amdgcn_s_setprio(0);
        barrier_pin();

        // ---- phase 3: A half1 ks1 ; tile-boundary drain ----
#pragma unroll
        for (int m = 0; m < 4; ++m) af[m] = *(const short8*)&a[(arow0 + 64 + m * 16) * 64 + k1];
        barrier_pin();
        lgkm0_fence();
        __builtin_amdgcn_s_setprio(1);
#pragma unroll
        for (int m = 0; m < 4; ++m)
#pragma unroll
            for (int n = 0; n < 4; ++n)
                acc[4 + m][n] = __builtin_amdgcn_mfma_f32_16x16x32_bf16(af[m], bw1[n], acc[4 + m][n], 0, 0, 0);
        __builtin_amdgcn_s_setprio(0);
        vwait<0>();          // kt+1 staging landed (issued 3 phases ago)
        barrier_pin();       // all waves' stages visible; buffer kt&1 free for kt+2
    }

    // epilogue: C/D layout col=lane&15, row=(lane>>4)*4+reg
    const int r4 = (lane >> 4) * 4;
#pragma unroll
    for (int m = 0; m < 8; ++m) {
#pragma unroll
        for (int n = 0; n < 4; ++n) {
            const int col = bn + wcN * 64 + n * 16 + lr16;
            const float bv = bias[col];
#pragma unroll
            for (int jj = 0; jj < 4; ++jj) {
                const int row = bm + wrM * 128 + m * 16 + r4 + jj;
                const float v = acc[m][n][jj] + bv;
                if (t0) store1(C0 + (size_t)row * ldc0 + col, v);
                else    store1(C1 + (size_t)row * ldc1 + col, v);
            }
        }
    }
}

// ---------------- O-projection GEMM, 128 x 64 tile, 16x16x32 (proven round-6) ----------
template <int BN, typename TC>
__global__ __launch_bounds__(256) void gemm128(
    const bf16* __restrict__ A, int lda, int cw, int rpx,
    const bf16* __restrict__ W0, int ldw0, const float* __restrict__ b0,
    TC* __restrict__ C0, int ldc0, int nt0, int nx0)
{
    constexpr int NF = BN / 32;
    constexpr int NLOAD = (BN == 128) ? 4 : 3;
    __shared__ short As[4][128 * 32];
    __shared__ short Bs[4][BN * 32];

    const int tid = threadIdx.x, wid = tid >> 6, lane = tid & 63;

    const int xcd = (int)blockIdx.x & 7;
    const int i   = (int)blockIdx.x >> 3;
    const int grp = rpx * cw;
    const int cc = i / grp, w2 = i % grp;
    const int rr = w2 / cw, c = w2 % cw;
    const int bx = cc * cw + c;
    const int by = xcd * rpx + rr;

    const int bm = by * 128;
    const int bn = bx * BN;
    const int nsteps = nt0;

    const int srow = lane >> 2;
    const int ssw  = (((lane & 3) ^ ((lane >> 3) & 3)) << 4);
    const char* pA0 = (const char*)A + (size_t)(bm + wid * 16 + srow) * lda * 2 + ssw;
    const char* pA1 = pA0 + (size_t)64 * lda * 2;
    const char* pB0 = (const char*)W0 + (size_t)(bn + wid * 16 + srow) * ldw0 * 2 + ssw;

    f32x4 acc[4][NF];
#pragma unroll
    for (int m = 0; m < 4; ++m)
#pragma unroll
        for (int n = 0; n < NF; ++n) acc[m][n] = f32x4{0.f, 0.f, 0.f, 0.f};

    const int lr16 = lane & 15;
    const int wsw8 = (((lane >> 4) ^ ((lr16 >> 1) & 3)) << 3);
    const int wr = wid >> 1, wc = wid & 1;
    int offA[4], offB[NF];
#pragma unroll
    for (int m = 0; m < 4; ++m) offA[m] = (wr * 4 + m) * 512 + lr16 * 32 + wsw8;
#pragma unroll
    for (int n = 0; n < NF; ++n) offB[n] = (wc * NF + n) * 512 + lr16 * 32 + wsw8;

    auto stage = [&](int buf) {
        gload_lds16(pA0, (char*)As[buf] + wid * 1024);
        gload_lds16(pA1, (char*)As[buf] + (wid + 4) * 1024);
        gload_lds16(pB0, (char*)Bs[buf] + wid * 1024);
        pA0 += 64; pA1 += 64; pB0 += 64;
    };

    stage(0);
    stage(1);
    stage(2);

    for (int s = 0; s < nsteps; ++s) {
        const int cur = s & 3;
        if (s + 3 < nsteps) {
            stage((s + 3) & 3);
            vwait<3 * NLOAD>();
        } else if (s + 2 < nsteps) {
            vwait<2 * NLOAD>();
        } else if (s + 1 < nsteps) {
            vwait<NLOAD>();
        } else {
            vwait<0>();
        }
        barrier_pin();

        short8 af[4], bw[NF];
#pragma unroll
        for (int m = 0; m < 4; ++m)
            af[m] = *(const short8*)&As[cur][offA[m]];
#pragma unroll
        for (int n = 0; n < NF; ++n)
            bw[n] = *(const short8*)&Bs[cur][offB[n]];

        __builtin_amdgcn_s_setprio(1);
#pragma unroll
        for (int m = 0; m < 4; ++m)
#pragma unroll
            for (int n = 0; n < NF; ++n)
                acc[m][n] = __builtin_amdgcn_mfma_f32_16x16x32_bf16(af[m], bw[n], acc[m][n], 0, 0, 0);
        __builtin_amdgcn_s_setprio(0);

        barrier_pin();
    }

    const int r4 = (lane >> 4) * 4;
#pragma unroll
    for (int m = 0; m < 4; ++m) {
#pragma unroll
        for (int n = 0; n < NF; ++n) {
            const int col = bn + wc * (NF * 16) + n * 16 + lr16;
            const float bv = b0[col];
#pragma unroll
            for (int jj = 0; jj < 4; ++jj) {
                const int row = bm + wr * 64 + m * 16 + r4 + jj;
                store1(C0 + (size_t)row * ldc0 + col, acc[m][n][jj] + bv);
            }
        }
    }
}

// ---------------- local attention stitch ----------------
__global__ __launch_bounds__(256) void attn_k(
    const bf16* __restrict__ PQK, const bf16* __restrict__ PV, bf16* __restrict__ Aout)
{
    const int lane = threadIdx.x & 63;
    const int wave = threadIdx.x >> 6;
    const int task = blockIdx.x * 4 + wave;  // 0..32767
    const int h  = task & 7;
    const int bl = task >> 3;
    const int l  = bl & 2047;
    const int d  = c_dil[h];

    const float q = __bfloat162float(PQK[(size_t)bl * 3072 + h * 64 + lane]);

    float logits[5], vvals[5];
#pragma unroll
    for (int kk = 0; kk < 5; ++kk) {
        const int pos = l + (kk - 2) * d;
        const bool ok = (pos >= 0) && (pos < 2048);
        float kv = 0.f, vv = 0.f;
        if (ok) {
            const size_t rb = (size_t)(bl - l + pos);
            kv = __bfloat162float(PQK[rb * 3072 + 512 + (h * 5 + kk) * 64 + lane]);
            vv = __bfloat162float(PV[rb * 2560 + (h * 5 + kk) * 64 + lane]);
        }
        vvals[kk] = vv;
        float lg = q * kv;
#pragma unroll
        for (int s = 32; s; s >>= 1) lg += __shfl_xor(lg, s);
        logits[kk] = lg;  // OOB -> 0, matches reference (zero-padded content, zero bias)
    }

    float mx = logits[0];
#pragma unroll
    for (int kk = 1; kk < 5; ++kk) mx = fmaxf(mx, logits[kk]);
    float e[5], ssum = 0.f;
#pragma unroll
    for (int kk = 0; kk < 5; ++kk) { e[kk] = __expf(logits[kk] - mx); ssum += e[kk]; }
    float acc = 0.f;
#pragma unroll
    for (int kk = 0; kk < 5; ++kk) acc += e[kk] * vvals[kk];
    acc *= 0.125f / ssum;

    Aout[(size_t)bl * 512 + h * 64 + lane] = __float2bfloat16(acc);
}

// ---------------- launch ----------------
extern "C" void kernel_launch(void* const* d_in, const int* in_sizes, int n_in,
                              void* d_out, int out_size, void* d_ws, size_t ws_size,
                              hipStream_t stream)
{
    const float* x   = (const float*)d_in[0];
    const float* q_w = (const float*)d_in[1];
    const float* q_b = (const float*)d_in[2];
    const float* k_w = (const float*)d_in[3];
    const float* k_b = (const float*)d_in[4];
    const float* v_w = (const float*)d_in[5];
    const float* v_b = (const float*)d_in[6];
    const float* o_w = (const float*)d_in[7];
    const float* o_b = (const float*)d_in[8];
    float* out = (float*)d_out;

    const int M = 4096;

    // workspace: 8 + 6 + 2.5 + 0.5 + 0.012 + 24 + 20 = 61.0 MB
    char* p = (char*)d_ws;
    bf16* A2  = (bf16*)p;  p += (size_t)M * 1024 * 2;       // [x_hi | x_lo]
    bf16* Wqk = (bf16*)p;  p += (size_t)3072 * 1024 * 2;    // [w_hi | w_hi]
    bf16* Wv  = (bf16*)p;  p += (size_t)2560 * 512 * 2;
    bf16* Wo  = (bf16*)p;  p += (size_t)512 * 512 * 2;
    float* bqk = (float*)p; p += 3072 * 4;
    bf16* PQK = (bf16*)p;  p += (size_t)M * 3072 * 2;
    bf16* PV  = (bf16*)p;
    bf16* Aout = A2;  // A2 dead after the QKV GEMM; reuse for attention output

    conv_all<<<dim3(5132), dim3(256), 0, stream>>>(x, q_w, k_w, v_w, o_w, q_b, k_b,
                                                   A2, Wqk, Wv, Wo, bqk);
    // fused QKV: col-tiles 0-11 -> PQK (K=1024 exact-x), 12-21 -> PV (K=512, hi half of A)
    // grid 352 = 8 XCD x (2 row-panels x 22 cols); QK cols dispatch first
    gemm8p<<<dim3(352), dim3(512), 0, stream>>>(
        A2, 1024,
        Wqk, 1024, bqk, PQK, 3072, 16, 12,
        Wv,  512,  v_b, PV,  2560, 8);
    attn_k<<<dim3(8192), dim3(256), 0, stream>>>(PQK, PV, Aout);
    // grid 256 = 8 XCD x (4 rows x 8 cols)
    gemm128<64, float><<<dim3(256), dim3(256), 0, stream>>>(
        Aout, 512, /*cw*/8, /*rpx*/4,
        Wo, 512, o_b, out, 512, 16, 8);
}

// Round 10
// 87.996 us; speedup vs baseline: 1.5734x; 1.0313x over previous
//
#include <hip/hip_runtime.h>
#include <hip/hip_bf16.h>

using bf16 = __hip_bfloat16;
typedef __attribute__((ext_vector_type(8))) short short8;
typedef __attribute__((ext_vector_type(4))) float f32x4;

__device__ __constant__ int c_dil[8] = {1, 2, 4, 8, 1, 2, 4, 8};

__device__ inline void store1(float* p, float v) { *p = v; }
__device__ inline void store1(bf16* p, float v) { *p = __float2bfloat16(v); }

// async global->LDS, 16 B per lane; LDS dest wave-uniform base (+ lane*16 by HW)
__device__ inline void gload_lds16(const void* g, void* l) {
    __builtin_amdgcn_global_load_lds(
        (const __attribute__((address_space(1))) unsigned int*)g,
        (__attribute__((address_space(3))) unsigned int*)l, 16, 0, 0);
}

template <int N> __device__ inline void vwait() {
    asm volatile("s_waitcnt vmcnt(%0)" :: "n"(N) : "memory");
}
__device__ inline void lgkm0_fence() {
    asm volatile("s_waitcnt lgkmcnt(0)" ::: "memory");
    __builtin_amdgcn_sched_barrier(0);
}
__device__ inline void barrier_pin() {
    __builtin_amdgcn_s_barrier();
    __builtin_amdgcn_sched_barrier(0);
}

// manual RNE f32->bf16
__device__ inline unsigned short f2bf(float f) {
    const unsigned u = __float_as_uint(f);
    return (unsigned short)((u + 0x7fffu + ((u >> 16) & 1u)) >> 16);
}
__device__ inline float bf2f(unsigned short h) { return __uint_as_float(((unsigned)h) << 16); }

// ---------------- fused convert: f32 -> bf16 ----------------
// mode 0: row = ld, plain;  mode 1: row = 1024, [hi|lo] (x);  mode 2: row = 1024, [hi|hi] (QK w)
__device__ inline void conv_block(const float* __restrict__ src, bf16* __restrict__ dst,
                                  int ld, int mode, int idx) {
    const float4 v = *reinterpret_cast<const float4*>(src + idx);
    const int r = idx >> 9, c = idx & 511;
    bf16* d = dst + (size_t)r * ld + c;
    const float vv[4] = {v.x, v.y, v.z, v.w};
    ushort4 hi, lo;
    unsigned short* hp = &hi.x; unsigned short* lp = &lo.x;
#pragma unroll
    for (int j = 0; j < 4; ++j) {
        hp[j] = f2bf(vv[j]);
        lp[j] = f2bf(vv[j] - bf2f(hp[j]));
    }
    *reinterpret_cast<ushort4*>(d) = hi;
    if (mode == 1) *reinterpret_cast<ushort4*>(d + 512) = lo;
    else if (mode == 2) *reinterpret_cast<ushort4*>(d + 512) = hi;
}

__global__ __launch_bounds__(256) void conv_all(
    const float* __restrict__ x,  const float* __restrict__ qw, const float* __restrict__ kw,
    const float* __restrict__ vw, const float* __restrict__ ow,
    const float* __restrict__ qb, const float* __restrict__ kb,
    bf16* A2, bf16* Wqk, bf16* Wv, bf16* Wo, float* bqk)
{
    const int b = blockIdx.x, t = threadIdx.x;
    if (b < 2048)       conv_block(x,  A2,                       1024, 1, (b * 256 + t) * 4);
    else if (b < 2304)  conv_block(qw, Wqk,                      1024, 2, ((b - 2048) * 256 + t) * 4);
    else if (b < 3584)  conv_block(kw, Wqk + (size_t)512 * 1024, 1024, 2, ((b - 2304) * 256 + t) * 4);
    else if (b < 4864)  conv_block(vw, Wv,                        512, 0, ((b - 3584) * 256 + t) * 4);
    else if (b < 5120)  conv_block(ow, Wo,                        512, 0, ((b - 4864) * 256 + t) * 4);
    else { const int i = (b - 5120) * 256 + t; bqk[i] = (i < 512) ? qb[i] : kb[i - 512]; }
}

// ---------------- 8-phase tile engine: 256 x (NB*64) tile, BK=64, 8 waves (2x4) --------
// Identical sync structure to the round-9 kernel (proven): per K-tile 4 phases of
// {ds_read subtile || prefetch -> barrier -> lgkmcnt(0) -> setprio(1) MFMA setprio(0)
// -> barrier}; vmcnt(0) only at the tile boundary. Swizzle: 16B slot within each 128 B
// row XORed with row&7, inverse-applied on the staging source (rule 21).
// NB = B-fragments per wave (4 -> BN=256, 5 -> BN=320).
template <int NB>
__device__ __forceinline__ void run_tile(
    short* AsB, short* BsB,                      // double buffers
    const bf16* __restrict__ A, int lda,
    const bf16* __restrict__ W, int ldw,
    const float* __restrict__ bias,
    bf16* __restrict__ C, int ldc,
    int bm, int bn, int nsteps)
{
    constexpr int ASTRIDE = 256 * 64;
    constexpr int BSTRIDE = 320 * 64;
    const int tid = threadIdx.x, wid = tid >> 6, lane = tid & 63;

    // staging source pointers (pre-swizzled slot within the 128 B row window)
    const int sslot = ((tid & 7) ^ ((tid >> 3) & 7)) << 4;
    const char* pA[4];
    const char* pB[NB];
#pragma unroll
    for (int i = 0; i < 4; ++i)
        pA[i] = (const char*)A + (size_t)(bm + i * 64 + (tid >> 3)) * lda * 2 + sslot;
#pragma unroll
    for (int i = 0; i < NB; ++i)
        pB[i] = (const char*)W + (size_t)(bn + i * 64 + (tid >> 3)) * ldw * 2 + sslot;

    auto stageA = [&](int kt1) {
        char* d = (char*)(AsB + (kt1 & 1) * ASTRIDE);
#pragma unroll
        for (int i = 0; i < 4; ++i) { gload_lds16(pA[i], d + i * 8192 + wid * 1024); pA[i] += 128; }
    };
    auto stageB = [&](int kt1) {
        char* d = (char*)(BsB + (kt1 & 1) * BSTRIDE);
#pragma unroll
        for (int i = 0; i < NB; ++i) { gload_lds16(pB[i], d + i * 8192 + wid * 1024); pB[i] += 128; }
    };

    f32x4 acc[8][NB];
#pragma unroll
    for (int m = 0; m < 8; ++m)
#pragma unroll
        for (int n = 0; n < NB; ++n) acc[m][n] = f32x4{0.f, 0.f, 0.f, 0.f};

    // read offsets (short units): off = row*64 + ((ks*32 + hi8) ^ swz); row&7 == lr16&7
    const int lr16 = lane & 15;
    const int hi8  = (lane >> 4) * 8;
    const int swz  = (lr16 & 7) << 3;
    const int k0   = hi8 ^ swz;
    const int k1   = (32 + hi8) ^ swz;
    const int wrM = wid >> 2, wcN = wid & 3;
    const int arow0 = wrM * 128 + lr16;
    const int brow0 = wcN * (NB * 16) + lr16;

    stageA(0); stageB(0);
    vwait<0>();
    barrier_pin();

    for (int kt = 0; kt < nsteps; ++kt) {
        const short* a  = AsB + (kt & 1) * ASTRIDE;
        const short* bb = BsB + (kt & 1) * BSTRIDE;
        const bool pf = (kt + 1 < nsteps);
        short8 af[4], bw0[NB], bw1[NB];

        // phase 0: A half0 ks0 + B ks0 ; prefetch A(kt+1)
#pragma unroll
        for (int m = 0; m < 4; ++m) af[m] = *(const short8*)&a[(arow0 + m * 16) * 64 + k0];
#pragma unroll
        for (int n = 0; n < NB; ++n) bw0[n] = *(const short8*)&bb[(brow0 + n * 16) * 64 + k0];
        if (pf) stageA(kt + 1);
        barrier_pin();
        lgkm0_fence();
        __builtin_amdgcn_s_setprio(1);
#pragma unroll
        for (int m = 0; m < 4; ++m)
#pragma unroll
            for (int n = 0; n < NB; ++n)
                acc[m][n] = __builtin_amdgcn_mfma_f32_16x16x32_bf16(af[m], bw0[n], acc[m][n], 0, 0, 0);
        __builtin_amdgcn_s_setprio(0);
        barrier_pin();

        // phase 1: A half1 ks0 ; prefetch B(kt+1)
#pragma unroll
        for (int m = 0; m < 4; ++m) af[m] = *(const short8*)&a[(arow0 + 64 + m * 16) * 64 + k0];
        if (pf) stageB(kt + 1);
        barrier_pin();
        lgkm0_fence();
        __builtin_amdgcn_s_setprio(1);
#pragma unroll
        for (int m = 0; m < 4; ++m)
#pragma unroll
            for (int n = 0; n < NB; ++n)
                acc[4 + m][n] = __builtin_amdgcn_mfma_f32_16x16x32_bf16(af[m], bw0[n], acc[4 + m][n], 0, 0, 0);
        __builtin_amdgcn_s_setprio(0);
        barrier_pin();

        // phase 2: A half0 ks1 + B ks1
#pragma unroll
        for (int m = 0; m < 4; ++m) af[m] = *(const short8*)&a[(arow0 + m * 16) * 64 + k1];
#pragma unroll
        for (int n = 0; n < NB; ++n) bw1[n] = *(const short8*)&bb[(brow0 + n * 16) * 64 + k1];
        barrier_pin();
        lgkm0_fence();
        __builtin_amdgcn_s_setprio(1);
#pragma unroll
        for (int m = 0; m < 4; ++m)
#pragma unroll
            for (int n = 0; n < NB; ++n)
                acc[m][n] = __builtin_amdgcn_mfma_f32_16x16x32_bf16(af[m], bw1[n], acc[m][n], 0, 0, 0);
        __builtin_amdgcn_s_setprio(0);
        barrier_pin();

        // phase 3: A half1 ks1 ; tile-boundary drain
#pragma unroll
        for (int m = 0; m < 4; ++m) af[m] = *(const short8*)&a[(arow0 + 64 + m * 16) * 64 + k1];
        barrier_pin();
        lgkm0_fence();
        __builtin_amdgcn_s_setprio(1);
#pragma unroll
        for (int m = 0; m < 4; ++m)
#pragma unroll
            for (int n = 0; n < NB; ++n)
                acc[4 + m][n] = __builtin_amdgcn_mfma_f32_16x16x32_bf16(af[m], bw1[n], acc[4 + m][n], 0, 0, 0);
        __builtin_amdgcn_s_setprio(0);
        vwait<0>();          // kt+1 staging landed (issued 2-3 phases ago)
        barrier_pin();       // all waves' stages visible; buffer kt&1 free for kt+2
    }

    // epilogue: C/D layout col=lane&15, row=(lane>>4)*4+reg
    const int r4 = (lane >> 4) * 4;
#pragma unroll
    for (int m = 0; m < 8; ++m) {
#pragma unroll
        for (int n = 0; n < NB; ++n) {
            const int col = bn + wcN * (NB * 16) + n * 16 + lr16;
            const float bv = bias[col];
#pragma unroll
            for (int jj = 0; jj < 4; ++jj) {
                const int row = bm + wrM * 128 + m * 16 + r4 + jj;
                store1(C + (size_t)row * ldc + col, acc[m][n][jj] + bv);
            }
        }
    }
}

// QKV GEMM, LPT-balanced grid of 320 jobs:
//   b <  192: QK tile 256x256, K=1024 (exact-x dup-weight schedule), 16 K-tiles
//   b >= 192: V  tile 256x320, K=512 (hi half of A), 8 K-tiles
__global__ __launch_bounds__(512, 1) void gemm8p(
    const bf16* __restrict__ A,
    const bf16* __restrict__ Wqk, const float* __restrict__ bqk, bf16* __restrict__ PQK,
    const bf16* __restrict__ Wv,  const float* __restrict__ vb,  bf16* __restrict__ PV)
{
    __shared__ short As[2 * 256 * 64];   // 64 KB
    __shared__ short Bs[2 * 320 * 64];   // 80 KB  (total 144 KB)

    const int b = blockIdx.x;
    if (b < 192) {
        const int xcd = b & 7, i = b >> 3;            // i: 0..23 -> 2 rows x 12 cols
        const int by = xcd * 2 + (i & 1), bx = i >> 1;
        run_tile<4>(As, Bs, A, 1024, Wqk, 1024, bqk, PQK, 3072, by * 256, bx * 256, 16);
    } else {
        const int v = b - 192;                        // 0..127
        const int xcd = v & 7, i = v >> 3;            // i: 0..15 -> 2 rows x 8 cols
        const int by = xcd * 2 + (i & 1), bx = i >> 1;
        run_tile<5>(As, Bs, A, 1024, Wv, 512, vb, PV, 2560, by * 256, bx * 320, 8);
    }
}

// ---------------- O-projection GEMM, 128 x 64 tile, 16x16x32 (proven round-6) ----------
template <int BN, typename TC>
__global__ __launch_bounds__(256) void gemm128(
    const bf16* __restrict__ A, int lda, int cw, int rpx,
    const bf16* __restrict__ W0, int ldw0, const float* __restrict__ b0,
    TC* __restrict__ C0, int ldc0, int nt0, int nx0)
{
    constexpr int NF = BN / 32;
    constexpr int NLOAD = (BN == 128) ? 4 : 3;
    __shared__ short As[4][128 * 32];
    __shared__ short Bs[4][BN * 32];

    const int tid = threadIdx.x, wid = tid >> 6, lane = tid & 63;

    const int xcd = (int)blockIdx.x & 7;
    const int i   = (int)blockIdx.x >> 3;
    const int grp = rpx * cw;
    const int cc = i / grp, w2 = i % grp;
    const int rr = w2 / cw, c = w2 % cw;
    const int bx = cc * cw + c;
    const int by = xcd * rpx + rr;

    const int bm = by * 128;
    const int bn = bx * BN;
    const int nsteps = nt0;

    const int srow = lane >> 2;
    const int ssw  = (((lane & 3) ^ ((lane >> 3) & 3)) << 4);
    const char* pA0 = (const char*)A + (size_t)(bm + wid * 16 + srow) * lda * 2 + ssw;
    const char* pA1 = pA0 + (size_t)64 * lda * 2;
    const char* pB0 = (const char*)W0 + (size_t)(bn + wid * 16 + srow) * ldw0 * 2 + ssw;

    f32x4 acc[4][NF];
#pragma unroll
    for (int m = 0; m < 4; ++m)
#pragma unroll
        for (int n = 0; n < NF; ++n) acc[m][n] = f32x4{0.f, 0.f, 0.f, 0.f};

    const int lr16 = lane & 15;
    const int wsw8 = (((lane >> 4) ^ ((lr16 >> 1) & 3)) << 3);
    const int wr = wid >> 1, wc = wid & 1;
    int offA[4], offB[NF];
#pragma unroll
    for (int m = 0; m < 4; ++m) offA[m] = (wr * 4 + m) * 512 + lr16 * 32 + wsw8;
#pragma unroll
    for (int n = 0; n < NF; ++n) offB[n] = (wc * NF + n) * 512 + lr16 * 32 + wsw8;

    auto stage = [&](int buf) {
        gload_lds16(pA0, (char*)As[buf] + wid * 1024);
        gload_lds16(pA1, (char*)As[buf] + (wid + 4) * 1024);
        gload_lds16(pB0, (char*)Bs[buf] + wid * 1024);
        pA0 += 64; pA1 += 64; pB0 += 64;
    };

    stage(0);
    stage(1);
    stage(2);

    for (int s = 0; s < nsteps; ++s) {
        const int cur = s & 3;
        if (s + 3 < nsteps) {
            stage((s + 3) & 3);
            vwait<3 * NLOAD>();
        } else if (s + 2 < nsteps) {
            vwait<2 * NLOAD>();
        } else if (s + 1 < nsteps) {
            vwait<NLOAD>();
        } else {
            vwait<0>();
        }
        barrier_pin();

        short8 af[4], bw[NF];
#pragma unroll
        for (int m = 0; m < 4; ++m)
            af[m] = *(const short8*)&As[cur][offA[m]];
#pragma unroll
        for (int n = 0; n < NF; ++n)
            bw[n] = *(const short8*)&Bs[cur][offB[n]];

        __builtin_amdgcn_s_setprio(1);
#pragma unroll
        for (int m = 0; m < 4; ++m)
#pragma unroll
            for (int n = 0; n < NF; ++n)
                acc[m][n] = __builtin_amdgcn_mfma_f32_16x16x32_bf16(af[m], bw[n], acc[m][n], 0, 0, 0);
        __builtin_amdgcn_s_setprio(0);

        barrier_pin();
    }

    const int r4 = (lane >> 4) * 4;
#pragma unroll
    for (int m = 0; m < 4; ++m) {
#pragma unroll
        for (int n = 0; n < NF; ++n) {
            const int col = bn + wc * (NF * 16) + n * 16 + lr16;
            const float bv = b0[col];
#pragma unroll
            for (int jj = 0; jj < 4; ++jj) {
                const int row = bm + wr * 64 + m * 16 + r4 + jj;
                store1(C0 + (size_t)row * ldc0 + col, acc[m][n][jj] + bv);
            }
        }
    }
}

// ---------------- local attention stitch ----------------
__global__ __launch_bounds__(256) void attn_k(
    const bf16* __restrict__ PQK, const bf16* __restrict__ PV, bf16* __restrict__ Aout)
{
    const int lane = threadIdx.x & 63;
    const int wave = threadIdx.x >> 6;
    const int task = blockIdx.x * 4 + wave;  // 0..32767
    const int h  = task & 7;
    const int bl = task >> 3;
    const int l  = bl & 2047;
    const int d  = c_dil[h];

    const float q = __bfloat162float(PQK[(size_t)bl * 3072 + h * 64 + lane]);

    float logits[5], vvals[5];
#pragma unroll
    for (int kk = 0; kk < 5; ++kk) {
        const int pos = l + (kk - 2) * d;
        const bool ok = (pos >= 0) && (pos < 2048);
        float kv = 0.f, vv = 0.f;
        if (ok) {
            const size_t rb = (size_t)(bl - l + pos);
            kv = __bfloat162float(PQK[rb * 3072 + 512 + (h * 5 + kk) * 64 + lane]);
            vv = __bfloat162float(PV[rb * 2560 + (h * 5 + kk) * 64 + lane]);
        }
        vvals[kk] = vv;
        float lg = q * kv;
#pragma unroll
        for (int s = 32; s; s >>= 1) lg += __shfl_xor(lg, s);
        logits[kk] = lg;  // OOB -> 0, matches reference (zero-padded content, zero bias)
    }

    float mx = logits[0];
#pragma unroll
    for (int kk = 1; kk < 5; ++kk) mx = fmaxf(mx, logits[kk]);
    float e[5], ssum = 0.f;
#pragma unroll
    for (int kk = 0; kk < 5; ++kk) { e[kk] = __expf(logits[kk] - mx); ssum += e[kk]; }
    float acc = 0.f;
#pragma unroll
    for (int kk = 0; kk < 5; ++kk) acc += e[kk] * vvals[kk];
    acc *= 0.125f / ssum;

    Aout[(size_t)bl * 512 + h * 64 + lane] = __float2bfloat16(acc);
}

// ---------------- launch ----------------
extern "C" void kernel_launch(void* const* d_in, const int* in_sizes, int n_in,
                              void* d_out, int out_size, void* d_ws, size_t ws_size,
                              hipStream_t stream)
{
    const float* x   = (const float*)d_in[0];
    const float* q_w = (const float*)d_in[1];
    const float* q_b = (const float*)d_in[2];
    const float* k_w = (const float*)d_in[3];
    const float* k_b = (const float*)d_in[4];
    const float* v_w = (const float*)d_in[5];
    const float* v_b = (const float*)d_in[6];
    const float* o_w = (const float*)d_in[7];
    const float* o_b = (const float*)d_in[8];
    float* out = (float*)d_out;

    const int M = 4096;

    // workspace: 8 + 6 + 2.5 + 0.5 + 0.012 + 24 + 20 = 61.0 MB
    char* p = (char*)d_ws;
    bf16* A2  = (bf16*)p;  p += (size_t)M * 1024 * 2;       // [x_hi | x_lo]
    bf16* Wqk = (bf16*)p;  p += (size_t)3072 * 1024 * 2;    // [w_hi | w_hi]
    bf16* Wv  = (bf16*)p;  p += (size_t)2560 * 512 * 2;
    bf16* Wo  = (bf16*)p;  p += (size_t)512 * 512 * 2;
    float* bqk = (float*)p; p += 3072 * 4;
    bf16* PQK = (bf16*)p;  p += (size_t)M * 3072 * 2;
    bf16* PV  = (bf16*)p;
    bf16* Aout = A2;  // A2 dead after the QKV GEMM; reuse for attention output

    conv_all<<<dim3(5132), dim3(256), 0, stream>>>(x, q_w, k_w, v_w, o_w, q_b, k_b,
                                                   A2, Wqk, Wv, Wo, bqk);
    // LPT-balanced QKV: 192 QK tiles (16kt) dispatch first, 128 V tiles (8kt) backfill
    gemm8p<<<dim3(320), dim3(512), 0, stream>>>(A2, Wqk, bqk, PQK, Wv, v_b, PV);
    attn_k<<<dim3(8192), dim3(256), 0, stream>>>(PQK, PV, Aout);
    // grid 256 = 8 XCD x (4 rows x 8 cols)
    gemm128<64, float><<<dim3(256), dim3(256), 0, stream>>>(
        Aout, 512, /*cw*/8, /*rpx*/4,
        Wo, 512, o_b, out, 512, 16, 8);
}

// Round 11
// 84.558 us; speedup vs baseline: 1.6374x; 1.0407x over previous
//
#include <hip/hip_runtime.h>
#include <hip/hip_bf16.h>

using bf16 = __hip_bfloat16;
typedef __attribute__((ext_vector_type(8))) short short8;
typedef __attribute__((ext_vector_type(4))) float f32x4;

__device__ __constant__ int c_dil[8] = {1, 2, 4, 8, 1, 2, 4, 8};

__device__ inline void store1(float* p, float v) { *p = v; }
__device__ inline void store1(bf16* p, float v) { *p = __float2bfloat16(v); }

// async global->LDS, 16 B per lane; LDS dest wave-uniform base (+ lane*16 by HW)
__device__ inline void gload_lds16(const void* g, void* l) {
    __builtin_amdgcn_global_load_lds(
        (const __attribute__((address_space(1))) unsigned int*)g,
        (__attribute__((address_space(3))) unsigned int*)l, 16, 0, 0);
}

template <int N> __device__ inline void vwait() {
    asm volatile("s_waitcnt vmcnt(%0)" :: "n"(N) : "memory");
    __builtin_amdgcn_sched_barrier(0);
}
__device__ inline void lgkm0_fence() {
    asm volatile("s_waitcnt lgkmcnt(0)" ::: "memory");
    __builtin_amdgcn_sched_barrier(0);
}
__device__ inline void barrier_pin() {
    __builtin_amdgcn_s_barrier();
    __builtin_amdgcn_sched_barrier(0);
}

// manual RNE f32->bf16
__device__ inline unsigned short f2bf(float f) {
    const unsigned u = __float_as_uint(f);
    return (unsigned short)((u + 0x7fffu + ((u >> 16) & 1u)) >> 16);
}
__device__ inline float bf2f(unsigned short h) { return __uint_as_float(((unsigned)h) << 16); }

// ---------------- fused convert: f32 -> bf16 ----------------
// mode 0: row = ld, plain;  mode 1: row = 1024, [hi|lo] (x)
__device__ inline void conv_block(const float* __restrict__ src, bf16* __restrict__ dst,
                                  int ld, int mode, int idx) {
    const float4 v = *reinterpret_cast<const float4*>(src + idx);
    const int r = idx >> 9, c = idx & 511;
    bf16* d = dst + (size_t)r * ld + c;
    const float vv[4] = {v.x, v.y, v.z, v.w};
    ushort4 hi, lo;
    unsigned short* hp = &hi.x; unsigned short* lp = &lo.x;
#pragma unroll
    for (int j = 0; j < 4; ++j) {
        hp[j] = f2bf(vv[j]);
        lp[j] = f2bf(vv[j] - bf2f(hp[j]));
    }
    *reinterpret_cast<ushort4*>(d) = hi;
    if (mode == 1) *reinterpret_cast<ushort4*>(d + 512) = lo;
}

__global__ __launch_bounds__(256) void conv_all(
    const float* __restrict__ x,  const float* __restrict__ qw, const float* __restrict__ kw,
    const float* __restrict__ vw, const float* __restrict__ ow,
    const float* __restrict__ qb, const float* __restrict__ kb,
    bf16* A2, bf16* Wqk, bf16* Wv, bf16* Wo, float* bqk)
{
    const int b = blockIdx.x, t = threadIdx.x;
    if (b < 2048)       conv_block(x,  A2,                      1024, 1, (b * 256 + t) * 4);
    else if (b < 2304)  conv_block(qw, Wqk,                      512, 0, ((b - 2048) * 256 + t) * 4);
    else if (b < 3584)  conv_block(kw, Wqk + (size_t)512 * 512,  512, 0, ((b - 2304) * 256 + t) * 4);
    else if (b < 4864)  conv_block(vw, Wv,                       512, 0, ((b - 3584) * 256 + t) * 4);
    else if (b < 5120)  conv_block(ow, Wo,                       512, 0, ((b - 4864) * 256 + t) * 4);
    else { const int i = (b - 5120) * 256 + t; bqk[i] = (i < 512) ? qb[i] : kb[i - 512]; }
}

// ======================= QK super-step engine (256x256, BK=64) =======================
// C = x_hi.w + x_lo.w with bw held in registers across both halves.
// Per super-step (64 K-cols of hi + same w vs 64 of lo): 4 phases, ONE barrier each:
//   ph0: rd af_hi k0 + bw0 | lgkm | BAR | stage Ahi(s+1) | 32 MFMA
//   ph1: rd af_hi k1 + bw1 | lgkm | vwait<4> (retire Alo(s)) | BAR | stage B(s+1) | 32 MFMA
//   ph2: rd af_lo k0       | lgkm | BAR | stage Alo(s+1) | 32 MFMA (reuse bw0)
//   ph3: rd af_lo k1       | lgkm | vwait<4> (retire Ahi/B(s+1) preds) | BAR | 32 MFMA (bw1)
// LDS: Ahi dbuf 2x32K + Alo dbuf 2x32K + B single 32K = 160 KB exact. Counted vmem waits
// only (T4); covers 2-3 phases. Swizzle identical to r10 (proven): 16B slot ^ (row&7),
// pre-applied on the global source, XOR-applied on the ds_read offset.
__device__ __forceinline__ void run_qk(
    short* smem,
    const bf16* __restrict__ A,            // [hi|lo], ld 1024
    const bf16* __restrict__ W,            // ld 512 (single copy)
    const float* __restrict__ bias,
    bf16* __restrict__ C,                  // ld 3072
    int bm, int bn)
{
    short* Ahi[2] = { smem,          smem + 16384 };
    short* Alo[2] = { smem + 32768,  smem + 49152 };
    short* Bb     =   smem + 65536;        // 256*64 shorts

    const int tid = threadIdx.x, wid = tid >> 6, lane = tid & 63;

    const int sslot = ((tid & 7) ^ ((tid >> 3) & 7)) << 4;   // bytes
    const char* pAh[4];
    const char* pAl[4];
    const char* pB[4];
#pragma unroll
    for (int i = 0; i < 4; ++i) {
        const int row = i * 64 + (tid >> 3);
        pAh[i] = (const char*)A + (size_t)(bm + row) * 2048 + sslot;           // lda 1024
        pAl[i] = pAh[i] + 1024;                                                // +512 cols
        pB[i]  = (const char*)W + (size_t)(bn + row) * 1024 + sslot;           // ldw 512
    }

    auto stageAhi = [&](int s1) {
        char* d = (char*)Ahi[s1 & 1];
#pragma unroll
        for (int i = 0; i < 4; ++i) { gload_lds16(pAh[i], d + i * 8192 + wid * 1024); pAh[i] += 128; }
    };
    auto stageAlo = [&](int s1) {
        char* d = (char*)Alo[s1 & 1];
#pragma unroll
        for (int i = 0; i < 4; ++i) { gload_lds16(pAl[i], d + i * 8192 + wid * 1024); pAl[i] += 128; }
    };
    auto stageB = [&]() {
        char* d = (char*)Bb;
#pragma unroll
        for (int i = 0; i < 4; ++i) { gload_lds16(pB[i], d + i * 8192 + wid * 1024); pB[i] += 128; }
    };

    f32x4 acc[8][4];
#pragma unroll
    for (int m = 0; m < 8; ++m)
#pragma unroll
        for (int n = 0; n < 4; ++n) acc[m][n] = f32x4{0.f, 0.f, 0.f, 0.f};

    const int lr16 = lane & 15;
    const int hi8  = (lane >> 4) * 8;
    const int swz  = (lr16 & 7) << 3;
    const int k0   = hi8 ^ swz;
    const int k1   = (32 + hi8) ^ swz;
    const int wrM = wid >> 2, wcN = wid & 3;
    const int arow0 = wrM * 128 + lr16;
    const int brow0 = wcN * 64 + lr16;

    // prologue: Ahi(0), B(0), Alo(0); retire Ahi+B, let Alo fly
    stageAhi(0); stageB(); stageAlo(0);
    vwait<4>();
    barrier_pin();

    short8 af[8], bw0[4], bw1[4];
    for (int s = 0; s < 8; ++s) {
        const short* ah = Ahi[s & 1];
        const short* al = Alo[s & 1];
        const bool pf = (s < 7);

        // ---- ph0: af_hi k0 + bw0 ----
#pragma unroll
        for (int m = 0; m < 8; ++m) af[m] = *(const short8*)&ah[(arow0 + m * 16) * 64 + k0];
#pragma unroll
        for (int n = 0; n < 4; ++n) bw0[n] = *(const short8*)&Bb[(brow0 + n * 16) * 64 + k0];
        lgkm0_fence();
        barrier_pin();
        if (pf) stageAhi(s + 1);
        __builtin_amdgcn_s_setprio(1);
#pragma unroll
        for (int m = 0; m < 8; ++m)
#pragma unroll
            for (int n = 0; n < 4; ++n)
                acc[m][n] = __builtin_amdgcn_mfma_f32_16x16x32_bf16(af[m], bw0[n], acc[m][n], 0, 0, 0);
        __builtin_amdgcn_s_setprio(0);

        // ---- ph1: af_hi k1 + bw1 ; retire Alo(s) ----
#pragma unroll
        for (int m = 0; m < 8; ++m) af[m] = *(const short8*)&ah[(arow0 + m * 16) * 64 + k1];
#pragma unroll
        for (int n = 0; n < 4; ++n) bw1[n] = *(const short8*)&Bb[(brow0 + n * 16) * 64 + k1];
        lgkm0_fence();
        if (pf) vwait<4>(); else vwait<0>();
        barrier_pin();
        if (pf) stageB();          // B slot safe: all waves' bw reads are in regs (lgkm before BAR)
        __builtin_amdgcn_s_setprio(1);
#pragma unroll
        for (int m = 0; m < 8; ++m)
#pragma unroll
            for (int n = 0; n < 4; ++n)
                acc[m][n] = __builtin_amdgcn_mfma_f32_16x16x32_bf16(af[m], bw1[n], acc[m][n], 0, 0, 0);
        __builtin_amdgcn_s_setprio(0);

        // ---- ph2: af_lo k0 (reuse bw0) ----
#pragma unroll
        for (int m = 0; m < 8; ++m) af[m] = *(const short8*)&al[(arow0 + m * 16) * 64 + k0];
        lgkm0_fence();
        barrier_pin();
        if (pf) stageAlo(s + 1);
        __builtin_amdgcn_s_setprio(1);
#pragma unroll
        for (int m = 0; m < 8; ++m)
#pragma unroll
            for (int n = 0; n < 4; ++n)
                acc[m][n] = __builtin_amdgcn_mfma_f32_16x16x32_bf16(af[m], bw0[n], acc[m][n], 0, 0, 0);
        __builtin_amdgcn_s_setprio(0);

        // ---- ph3: af_lo k1 (reuse bw1) ; retire Ahi(s+1), B(s+1) ----
#pragma unroll
        for (int m = 0; m < 8; ++m) af[m] = *(const short8*)&al[(arow0 + m * 16) * 64 + k1];
        lgkm0_fence();
        vwait<4>();               // leaves Alo(s+1) in flight
        barrier_pin();
        __builtin_amdgcn_s_setprio(1);
#pragma unroll
        for (int m = 0; m < 8; ++m)
#pragma unroll
            for (int n = 0; n < 4; ++n)
                acc[m][n] = __builtin_amdgcn_mfma_f32_16x16x32_bf16(af[m], bw1[n], acc[m][n], 0, 0, 0);
        __builtin_amdgcn_s_setprio(0);
        barrier_pin();
    }

    // epilogue: C/D layout col=lane&15, row=(lane>>4)*4+reg
    const int r4 = (lane >> 4) * 4;
#pragma unroll
    for (int m = 0; m < 8; ++m) {
#pragma unroll
        for (int n = 0; n < 4; ++n) {
            const int col = bn + wcN * 64 + n * 16 + lr16;
            const float bv = bias[col];
#pragma unroll
            for (int jj = 0; jj < 4; ++jj) {
                const int row = bm + wrM * 128 + m * 16 + r4 + jj;
                store1(C + (size_t)row * 3072 + col, acc[m][n][jj] + bv);
            }
        }
    }
}

// ======================= V engine: r10's proven 4-phase run_tile, NB=5 ================
__device__ __forceinline__ void run_v(
    short* smem,
    const bf16* __restrict__ A,            // hi half, ld 1024
    const bf16* __restrict__ W,            // ld 512
    const float* __restrict__ bias,
    bf16* __restrict__ C,                  // ld 2560
    int bm, int bn)
{
    constexpr int NB = 5;
    short* AsB = smem;                     // 2 x 16384 shorts
    short* BsB = smem + 32768;             // 2 x 20480 shorts
    constexpr int ASTRIDE = 256 * 64;
    constexpr int BSTRIDE = 320 * 64;
    const int tid = threadIdx.x, wid = tid >> 6, lane = tid & 63;
    const int nsteps = 8;

    const int sslot = ((tid & 7) ^ ((tid >> 3) & 7)) << 4;
    const char* pA[4];
    const char* pB[NB];
#pragma unroll
    for (int i = 0; i < 4; ++i)
        pA[i] = (const char*)A + (size_t)(bm + i * 64 + (tid >> 3)) * 2048 + sslot;
#pragma unroll
    for (int i = 0; i < NB; ++i)
        pB[i] = (const char*)W + (size_t)(bn + i * 64 + (tid >> 3)) * 1024 + sslot;

    auto stageA = [&](int kt1) {
        char* d = (char*)(AsB + (kt1 & 1) * ASTRIDE);
#pragma unroll
        for (int i = 0; i < 4; ++i) { gload_lds16(pA[i], d + i * 8192 + wid * 1024); pA[i] += 128; }
    };
    auto stageB = [&](int kt1) {
        char* d = (char*)(BsB + (kt1 & 1) * BSTRIDE);
#pragma unroll
        for (int i = 0; i < NB; ++i) { gload_lds16(pB[i], d + i * 8192 + wid * 1024); pB[i] += 128; }
    };

    f32x4 acc[8][NB];
#pragma unroll
    for (int m = 0; m < 8; ++m)
#pragma unroll
        for (int n = 0; n < NB; ++n) acc[m][n] = f32x4{0.f, 0.f, 0.f, 0.f};

    const int lr16 = lane & 15;
    const int hi8  = (lane >> 4) * 8;
    const int swz  = (lr16 & 7) << 3;
    const int k0   = hi8 ^ swz;
    const int k1   = (32 + hi8) ^ swz;
    const int wrM = wid >> 2, wcN = wid & 3;
    const int arow0 = wrM * 128 + lr16;
    const int brow0 = wcN * (NB * 16) + lr16;

    stageA(0); stageB(0);
    vwait<0>();
    barrier_pin();

    for (int kt = 0; kt < nsteps; ++kt) {
        const short* a  = AsB + (kt & 1) * ASTRIDE;
        const short* bb = BsB + (kt & 1) * BSTRIDE;
        const bool pf = (kt + 1 < nsteps);
        short8 af[4], bw0[NB], bw1[NB];

#pragma unroll
        for (int m = 0; m < 4; ++m) af[m] = *(const short8*)&a[(arow0 + m * 16) * 64 + k0];
#pragma unroll
        for (int n = 0; n < NB; ++n) bw0[n] = *(const short8*)&bb[(brow0 + n * 16) * 64 + k0];
        if (pf) stageA(kt + 1);
        barrier_pin();
        lgkm0_fence();
        __builtin_amdgcn_s_setprio(1);
#pragma unroll
        for (int m = 0; m < 4; ++m)
#pragma unroll
            for (int n = 0; n < NB; ++n)
                acc[m][n] = __builtin_amdgcn_mfma_f32_16x16x32_bf16(af[m], bw0[n], acc[m][n], 0, 0, 0);
        __builtin_amdgcn_s_setprio(0);
        barrier_pin();

#pragma unroll
        for (int m = 0; m < 4; ++m) af[m] = *(const short8*)&a[(arow0 + 64 + m * 16) * 64 + k0];
        if (pf) stageB(kt + 1);
        barrier_pin();
        lgkm0_fence();
        __builtin_amdgcn_s_setprio(1);
#pragma unroll
        for (int m = 0; m < 4; ++m)
#pragma unroll
            for (int n = 0; n < NB; ++n)
                acc[4 + m][n] = __builtin_amdgcn_mfma_f32_16x16x32_bf16(af[m], bw0[n], acc[4 + m][n], 0, 0, 0);
        __builtin_amdgcn_s_setprio(0);
        barrier_pin();

#pragma unroll
        for (int m = 0; m < 4; ++m) af[m] = *(const short8*)&a[(arow0 + m * 16) * 64 + k1];
#pragma unroll
        for (int n = 0; n < NB; ++n) bw1[n] = *(const short8*)&bb[(brow0 + n * 16) * 64 + k1];
        barrier_pin();
        lgkm0_fence();
        __builtin_amdgcn_s_setprio(1);
#pragma unroll
        for (int m = 0; m < 4; ++m)
#pragma unroll
            for (int n = 0; n < NB; ++n)
                acc[m][n] = __builtin_amdgcn_mfma_f32_16x16x32_bf16(af[m], bw1[n], acc[m][n], 0, 0, 0);
        __builtin_amdgcn_s_setprio(0);
        barrier_pin();

#pragma unroll
        for (int m = 0; m < 4; ++m) af[m] = *(const short8*)&a[(arow0 + 64 + m * 16) * 64 + k1];
        barrier_pin();
        lgkm0_fence();
        __builtin_amdgcn_s_setprio(1);
#pragma unroll
        for (int m = 0; m < 4; ++m)
#pragma unroll
            for (int n = 0; n < NB; ++n)
                acc[4 + m][n] = __builtin_amdgcn_mfma_f32_16x16x32_bf16(af[m], bw1[n], acc[4 + m][n], 0, 0, 0);
        __builtin_amdgcn_s_setprio(0);
        vwait<0>();
        barrier_pin();
    }

    const int r4 = (lane >> 4) * 4;
#pragma unroll
    for (int m = 0; m < 8; ++m) {
#pragma unroll
        for (int n = 0; n < NB; ++n) {
            const int col = bn + wcN * (NB * 16) + n * 16 + lr16;
            const float bv = bias[col];
#pragma unroll
            for (int jj = 0; jj < 4; ++jj) {
                const int row = bm + wrM * 128 + m * 16 + r4 + jj;
                store1(C + (size_t)row * 2560 + col, acc[m][n][jj] + bv);
            }
        }
    }
}

// LPT grid of 320 jobs: b<192 QK (8 super-steps), b>=192 V (8 kt, BN=320)
__global__ __launch_bounds__(512, 1) void gemm8p(
    const bf16* __restrict__ A,
    const bf16* __restrict__ Wqk, const float* __restrict__ bqk, bf16* __restrict__ PQK,
    const bf16* __restrict__ Wv,  const float* __restrict__ vb,  bf16* __restrict__ PV)
{
    __shared__ short smem[81920];   // 160 KB
    const int b = blockIdx.x;
    if (b < 192) {
        const int xcd = b & 7, i = b >> 3;
        const int by = xcd * 2 + (i & 1), bx = i >> 1;   // 16 rows x 12 cols
        run_qk(smem, A, Wqk, bqk, PQK, by * 256, bx * 256);
    } else {
        const int v = b - 192;
        const int xcd = v & 7, i = v >> 3;
        const int by = xcd * 2 + (i & 1), bx = i >> 1;   // 16 rows x 8 cols
        run_v(smem, A, Wv, vb, PV, by * 256, bx * 320);
    }
}

// ---------------- O-projection GEMM, 128 x 64 tile, 16x16x32 (proven round-6) ----------
template <int BN, typename TC>
__global__ __launch_bounds__(256) void gemm128(
    const bf16* __restrict__ A, int lda, int cw, int rpx,
    const bf16* __restrict__ W0, int ldw0, const float* __restrict__ b0,
    TC* __restrict__ C0, int ldc0, int nt0, int nx0)
{
    constexpr int NF = BN / 32;
    constexpr int NLOAD = (BN == 128) ? 4 : 3;
    __shared__ short As[4][128 * 32];
    __shared__ short Bs[4][BN * 32];

    const int tid = threadIdx.x, wid = tid >> 6, lane = tid & 63;

    const int xcd = (int)blockIdx.x & 7;
    const int i   = (int)blockIdx.x >> 3;
    const int grp = rpx * cw;
    const int cc = i / grp, w2 = i % grp;
    const int rr = w2 / cw, c = w2 % cw;
    const int bx = cc * cw + c;
    const int by = xcd * rpx + rr;

    const int bm = by * 128;
    const int bn = bx * BN;
    const int nsteps = nt0;

    const int srow = lane >> 2;
    const int ssw  = (((lane & 3) ^ ((lane >> 3) & 3)) << 4);
    const char* pA0 = (const char*)A + (size_t)(bm + wid * 16 + srow) * lda * 2 + ssw;
    const char* pA1 = pA0 + (size_t)64 * lda * 2;
    const char* pB0 = (const char*)W0 + (size_t)(bn + wid * 16 + srow) * ldw0 * 2 + ssw;

    f32x4 acc[4][NF];
#pragma unroll
    for (int m = 0; m < 4; ++m)
#pragma unroll
        for (int n = 0; n < NF; ++n) acc[m][n] = f32x4{0.f, 0.f, 0.f, 0.f};

    const int lr16 = lane & 15;
    const int wsw8 = (((lane >> 4) ^ ((lr16 >> 1) & 3)) << 3);
    const int wr = wid >> 1, wc = wid & 1;
    int offA[4], offB[NF];
#pragma unroll
    for (int m = 0; m < 4; ++m) offA[m] = (wr * 4 + m) * 512 + lr16 * 32 + wsw8;
#pragma unroll
    for (int n = 0; n < NF; ++n) offB[n] = (wc * NF + n) * 512 + lr16 * 32 + wsw8;

    auto stage = [&](int buf) {
        gload_lds16(pA0, (char*)As[buf] + wid * 1024);
        gload_lds16(pA1, (char*)As[buf] + (wid + 4) * 1024);
        gload_lds16(pB0, (char*)Bs[buf] + wid * 1024);
        pA0 += 64; pA1 += 64; pB0 += 64;
    };

    stage(0);
    stage(1);
    stage(2);

    for (int s = 0; s < nsteps; ++s) {
        const int cur = s & 3;
        if (s + 3 < nsteps) {
            stage((s + 3) & 3);
            vwait<3 * NLOAD>();
        } else if (s + 2 < nsteps) {
            vwait<2 * NLOAD>();
        } else if (s + 1 < nsteps) {
            vwait<NLOAD>();
        } else {
            vwait<0>();
        }
        barrier_pin();

        short8 af[4], bw[NF];
#pragma unroll
        for (int m = 0; m < 4; ++m)
            af[m] = *(const short8*)&As[cur][offA[m]];
#pragma unroll
        for (int n = 0; n < NF; ++n)
            bw[n] = *(const short8*)&Bs[cur][offB[n]];

        __builtin_amdgcn_s_setprio(1);
#pragma unroll
        for (int m = 0; m < 4; ++m)
#pragma unroll
            for (int n = 0; n < NF; ++n)
                acc[m][n] = __builtin_amdgcn_mfma_f32_16x16x32_bf16(af[m], bw[n], acc[m][n], 0, 0, 0);
        __builtin_amdgcn_s_setprio(0);

        barrier_pin();
    }

    const int r4 = (lane >> 4) * 4;
#pragma unroll
    for (int m = 0; m < 4; ++m) {
#pragma unroll
        for (int n = 0; n < NF; ++n) {
            const int col = bn + wc * (NF * 16) + n * 16 + lr16;
            const float bv = b0[col];
#pragma unroll
            for (int jj = 0; jj < 4; ++jj) {
                const int row = bm + wr * 64 + m * 16 + r4 + jj;
                store1(C0 + (size_t)row * ldc0 + col, acc[m][n][jj] + bv);
            }
        }
    }
}

// ---------------- local attention stitch ----------------
__global__ __launch_bounds__(256) void attn_k(
    const bf16* __restrict__ PQK, const bf16* __restrict__ PV, bf16* __restrict__ Aout)
{
    const int lane = threadIdx.x & 63;
    const int wave = threadIdx.x >> 6;
    const int task = blockIdx.x * 4 + wave;  // 0..32767
    const int h  = task & 7;
    const int bl = task >> 3;
    const int l  = bl & 2047;
    const int d  = c_dil[h];

    const float q = __bfloat162float(PQK[(size_t)bl * 3072 + h * 64 + lane]);

    float logits[5], vvals[5];
#pragma unroll
    for (int kk = 0; kk < 5; ++kk) {
        const int pos = l + (kk - 2) * d;
        const bool ok = (pos >= 0) && (pos < 2048);
        float kv = 0.f, vv = 0.f;
        if (ok) {
            const size_t rb = (size_t)(bl - l + pos);
            kv = __bfloat162float(PQK[rb * 3072 + 512 + (h * 5 + kk) * 64 + lane]);
            vv = __bfloat162float(PV[rb * 2560 + (h * 5 + kk) * 64 + lane]);
        }
        vvals[kk] = vv;
        float lg = q * kv;
#pragma unroll
        for (int s = 32; s; s >>= 1) lg += __shfl_xor(lg, s);
        logits[kk] = lg;  // OOB -> 0, matches reference (zero-padded content, zero bias)
    }

    float mx = logits[0];
#pragma unroll
    for (int kk = 1; kk < 5; ++kk) mx = fmaxf(mx, logits[kk]);
    float e[5], ssum = 0.f;
#pragma unroll
    for (int kk = 0; kk < 5; ++kk) { e[kk] = __expf(logits[kk] - mx); ssum += e[kk]; }
    float acc = 0.f;
#pragma unroll
    for (int kk = 0; kk < 5; ++kk) acc += e[kk] * vvals[kk];
    acc *= 0.125f / ssum;

    Aout[(size_t)bl * 512 + h * 64 + lane] = __float2bfloat16(acc);
}

// ---------------- launch ----------------
extern "C" void kernel_launch(void* const* d_in, const int* in_sizes, int n_in,
                              void* d_out, int out_size, void* d_ws, size_t ws_size,
                              hipStream_t stream)
{
    const float* x   = (const float*)d_in[0];
    const float* q_w = (const float*)d_in[1];
    const float* q_b = (const float*)d_in[2];
    const float* k_w = (const float*)d_in[3];
    const float* k_b = (const float*)d_in[4];
    const float* v_w = (const float*)d_in[5];
    const float* v_b = (const float*)d_in[6];
    const float* o_w = (const float*)d_in[7];
    const float* o_b = (const float*)d_in[8];
    float* out = (float*)d_out;

    const int M = 4096;

    // workspace: A2 8 + Wqk 3 + Wv 2.5 + Wo 0.5 + bqk 0.012 + PQK 24 + PV 20 = 58 MB
    char* p = (char*)d_ws;
    bf16* A2  = (bf16*)p;  p += (size_t)M * 1024 * 2;       // [x_hi | x_lo]
    bf16* Wqk = (bf16*)p;  p += (size_t)3072 * 512 * 2;     // single w_hi copy
    bf16* Wv  = (bf16*)p;  p += (size_t)2560 * 512 * 2;
    bf16* Wo  = (bf16*)p;  p += (size_t)512 * 512 * 2;
    float* bqk = (float*)p; p += 3072 * 4;
    bf16* PQK = (bf16*)p;  p += (size_t)M * 3072 * 2;
    bf16* PV  = (bf16*)p;
    bf16* Aout = A2;  // A2 dead after the QKV GEMM; reuse for attention output

    conv_all<<<dim3(5132), dim3(256), 0, stream>>>(x, q_w, k_w, v_w, o_w, q_b, k_b,
                                                   A2, Wqk, Wv, Wo, bqk);
    // LPT QKV: 192 QK super-step blocks first, 128 V blocks backfill
    gemm8p<<<dim3(320), dim3(512), 0, stream>>>(A2, Wqk, bqk, PQK, Wv, v_b, PV);
    attn_k<<<dim3(8192), dim3(256), 0, stream>>>(PQK, PV, Aout);
    // grid 256 = 8 XCD x (4 rows x 8 cols)
    gemm128<64, float><<<dim3(256), dim3(256), 0, stream>>>(
        Aout, 512, /*cw*/8, /*rpx*/4,
        Wo, 512, o_b, out, 512, 16, 8);
}